// Round 6
// baseline (256.738 us; speedup 1.0000x reference)
//
#include <hip/hip_runtime.h>
#include <stdint.h>

// RandomMaskSubgraphs — round 19: amortize/de-contend the two remaining spots.
// r18 confirmed (matched prediction): fat append blocks -20%; fill kernel
// (354MB @ 84% BW, ~55us) is harness-side, uncontrollable.
// r19a: CURSTRIDE 4->16 — each bucket cursor gets a private 64B line; append's
//       reserve phase (1024 global atomics/block between two barriers) loses
//       4x line false-sharing (was 1820 atomics/line on 256 lines).
// r19b: k_dedup 512-thread/2-bucket blocks (1024->512 blocks): two independent
//       256-thread halves share one dispatch+barriers; LDS 74.6KB -> 2/CU ->
//       same 16 waves/CU residency, half the per-bucket dispatch/barrier cost
//       (r17 mechanism transferred). Blocks >=500 idle out (rowbase>=NN).
// RULE (r16): never trade a kernel boundary for an intra-kernel grid sync.
// k_append r18 geometry (APPT=512/EPB=5632/NE=11); PRNG v0 bit-exact.

#define NN 40000
#define SAMPN (NN / 2)
#define WORDS 1250               // col bitmap words (40000/32)
#define SWORDS 40                // summary words
#define NB 1024                  // buckets (append bins == dedup buckets)
#define RPB 40                   // rows per bucket (1024*40 >= 40000)
#define CAP 8192                 // entries per bucket (mean ~5.3k)
#define CURSTRIDE 16             // 64B per cursor: no false sharing
#define APPT 512                 // k_append threads per block
#define EPB 5632                 // edges per append block (11*512)
#define NE (EPB / APPT)          // 11 edges per thread
#define SELFPB 88                // self nodes per append block (455*88 >= 40000)
#define SCAP (3 * EPB + SELFPB)  // 16984 -> 67.9 KB
#define MWPB 250                 // mask words per extract block (40*250=10000)
#define DT 512                   // k_dedup threads (2 buckets per block)

// ---------------- Threefry-2x32 (20 rounds, JAX schedule) ----------------
__host__ __device__ __forceinline__ void tf2x32(unsigned k0, unsigned k1,
                                                unsigned x0, unsigned x1,
                                                unsigned &o0, unsigned &o1) {
  unsigned ks2 = k0 ^ k1 ^ 0x1BD11BDAu;
  x0 += k0; x1 += k1;
#define TFR(r) { x0 += x1; x1 = (x1 << (r)) | (x1 >> (32 - (r))); x1 ^= x0; }
  TFR(13) TFR(15) TFR(26) TFR(6)
  x0 += k1;  x1 += ks2 + 1u;
  TFR(17) TFR(29) TFR(16) TFR(24)
  x0 += ks2; x1 += k0 + 2u;
  TFR(13) TFR(15) TFR(26) TFR(6)
  x0 += k0;  x1 += k1 + 3u;
  TFR(17) TFR(29) TFR(16) TFR(24)
  x0 += k1;  x1 += ks2 + 4u;
  TFR(13) TFR(15) TFR(26) TFR(6)
  x0 += ks2; x1 += k0 + 5u;
#undef TFR
  o0 = x0; o1 = x1;
}

// jax.random.randint element e with pre-split subkeys k1=(a,b), k2=(c,d).
// m2 = ((65536 % span)^2) % span, precomputed by the caller (span-invariant).
__device__ __forceinline__ unsigned jrand(unsigned a, unsigned b, unsigned c,
                                          unsigned d, unsigned e, unsigned span,
                                          unsigned m2) {
  unsigned x0, x1, y0, y1;
  tf2x32(a, b, 0u, e, x0, x1);
  unsigned hi = x0 ^ x1;
  tf2x32(c, d, 0u, e, y0, y1);
  unsigned lo = y0 ^ y1;
  return ((hi % span) * m2 + (lo % span)) % span;
}

// ---------------- init / BFS ----------------
__global__ void k_zero16(uint4 *p, int n16) {
  int i = blockIdx.x * blockDim.x + threadIdx.x;
  if (i < n16) p[i] = make_uint4(0u, 0u, 0u, 0u);
}
__global__ void k_seed_samp(const int *seeds, int ns, unsigned char *cur,
                            unsigned char *mask_bfs,
                            unsigned a, unsigned b, unsigned c, unsigned d) {
  int i = blockIdx.x * blockDim.x + threadIdx.x;
  if (i < ns) { int s = seeds[i]; cur[s] = 1; mask_bfs[s] = 1; }
  if (i < SAMPN) {
    constexpr unsigned M2 =
        ((65536u % (unsigned)NN) * (65536u % (unsigned)NN)) % (unsigned)NN;
    unsigned idx = jrand(a, b, c, d, (unsigned)i, (unsigned)NN, M2);
    mask_bfs[idx] = 1;
  }
}
// level-0 BFS; also zeroes deg + cursors (used by later kernels only).
__global__ void k_level0(const int *rows, const int *cols, int E,
                         const unsigned char *cur, unsigned char *alive,
                         unsigned char *touched, unsigned char *mask_bfs,
                         int *deg, int *cursors) {
  int e = blockIdx.x * blockDim.x + threadIdx.x;
  if (e < NN) deg[e] = 0;
  int e2 = e - NN;
  if (e2 >= 0 && e2 < NB * CURSTRIDE) cursors[e2] = 0;
  if (e >= E) return;
  int r = rows[e], c = cols[e];
  if (cur[r] | cur[c]) {
    alive[e] = 0;
    touched[r] = 1; touched[c] = 1;
    mask_bfs[r] = 1; mask_bfs[c] = 1;
  } else alive[e] = 1;
}
// level-1 BFS + degree; blocks 0..39 also compute mask popcount partials
// (mask_bfs is complete before this kernel launches).
__global__ void k_level1_deg(const int *rows, const int *cols, int E,
                             const unsigned char *touched, unsigned char *alive,
                             int *deg, const unsigned *maskw, int *mask_part) {
  int tid = threadIdx.x;
  int e = blockIdx.x * blockDim.x + tid;
  if (e < E && alive[e]) {
    int r = rows[e];
    if (touched[r] | touched[cols[e]]) alive[e] = 0;
    else atomicAdd(&deg[r], 1);
  }
  if (blockIdx.x < 40) {
    __shared__ int red[4];
    int lane = tid & 63, wid = tid >> 6;
    int c = (tid < MWPB) ? __popc(maskw[blockIdx.x * MWPB + tid]) : 0;
    for (int d = 1; d < 64; d <<= 1) c += __shfl_xor(c, d, 64);
    if (lane == 0) red[wid] = c;
    __syncthreads();
    if (tid == 0) mask_part[blockIdx.x] = red[0] + red[1] + red[2] + red[3];
  }
}

// ---------------- mask extraction (40 blocks; replaces 1-block scan) --------
__global__ __launch_bounds__(256) void k_mask_extract(const unsigned *f,
                                                      const int *mask_part,
                                                      unsigned short *mask_idx,
                                                      int *tem_num) {
  __shared__ int wsum[4];
  __shared__ int basech;
  int b = blockIdx.x, tid = threadIdx.x, lane = tid & 63, wid = tid >> 6;
  if (wid == 0) {
    int v = (lane < 40) ? mask_part[lane] : 0;
    int x = v;
    for (int d = 1; d < 64; d <<= 1) {
      int y = __shfl_up(x, d, 64);
      if (lane >= d) x += y;
    }
    int basev = __shfl(x - v, b, 64);   // exclusive prefix at own block
    int total = __shfl(x, 39, 64);
    if (lane == 0) {
      basech = basev;
      if (b == 0) *tem_num = total;
    }
  }
  int w = b * MWPB + tid;
  unsigned u = (tid < MWPB) ? f[w] : 0u;
  int c = __popc(u);
  int x = c;
  for (int d = 1; d < 64; d <<= 1) {
    int y = __shfl_up(x, d, 64);
    if (lane >= d) x += y;
  }
  if (lane == 63) wsum[wid] = x;
  __syncthreads();
  if (wid == 0) {
    int v = (lane < 4) ? wsum[lane] : 0;
    int y = v;
    for (int d = 1; d < 4; d <<= 1) {
      int z = __shfl_up(y, d, 64);
      if (lane >= d) y += z;
    }
    if (lane < 4) wsum[lane] = y - v;
  }
  __syncthreads();
  int off = basech + wsum[wid] + (x - c);
  while (u) {
    int byte = (__ffs(u) - 1) >> 3;
    u &= u - 1;
    mask_idx[off++] = (unsigned short)(w * 4 + byte);
  }
}

// ---------------- binned append (tem + alive + self) + fused encoder ----------
__global__ __launch_bounds__(APPT) void k_append(
    const int *rows, const int *cols, const unsigned char *alive,
    const int *deg, const unsigned short *mask_idx, const int *tem_num,
    int *cursors, unsigned *bucketmem, float *out,
    unsigned ra, unsigned rb, unsigned rc, unsigned rd,
    unsigned ca, unsigned cb, unsigned cc, unsigned cd, int E) {
  __shared__ unsigned sorted[SCAP];     // 67.9 KB
  __shared__ int cnt[NB];               // 4 KB
  __shared__ unsigned short ofs[NB];    // 2 KB
  __shared__ int ntot_s;
  int tid = threadIdx.x, lane = tid & 63, wid = tid >> 6;
  int e0 = blockIdx.x * EPB;
  int i0 = blockIdx.x * SELFPB;         // self-node range
  int i1 = i0 + SELFPB; if (i1 > NN) i1 = NN;
  unsigned span = (unsigned)*tem_num;
  unsigned mtmp = 65536u % span;
  unsigned m2 = (mtmp * mtmp) % span;   // hoisted out of jrand (span-invariant)
  const unsigned NOPE = 0xFFFFFFFFu;

  unsigned tval[NE], aval[NE];

  for (int i = tid; i < NB; i += APPT) cnt[i] = 0;
  __syncthreads();
  // pass A: draw + gather once, count, cache in registers; fused encoder out
#pragma unroll
  for (int k = 0; k < NE; k++) {
    int e = e0 + k * APPT + tid;
    if (e < E) {
      unsigned iR = jrand(ra, rb, rc, rd, (unsigned)e, span, m2);
      unsigned iC = jrand(ca, cb, cc, cd, (unsigned)e, span, m2);
      unsigned tr = (unsigned)mask_idx[iR], tc = (unsigned)mask_idx[iC];
      tval[k] = (tr << 16) | tc;
      atomicAdd(&cnt[tr / RPB], 1);
      atomicAdd(&cnt[tc / RPB], 1);
      int r = rows[e], c = cols[e];
      float v = 0.0f;
      if (alive[e]) {
        aval[k] = ((unsigned)r << 16) | (unsigned)c;
        atomicAdd(&cnt[(unsigned)r / RPB], 1);
        float xr = (float)deg[r] + 1e-12f;
        float xc = (float)deg[c] + 1e-12f;
        float dr = (float)(1.0 / sqrt((double)xr));
        float dc = (float)(1.0 / sqrt((double)xc));
        v = dr * dc;
      } else aval[k] = NOPE;
      out[e] = (float)r;
      out[E + e] = (float)c;
      out[2 * E + e] = v;
    } else { tval[k] = NOPE; aval[k] = NOPE; }
  }
  for (int i = i0 + tid; i < i1; i += APPT) atomicAdd(&cnt[i / RPB], 1);
  __syncthreads();
  // exclusive scan of cnt[1024] by wave 0 -> ofs (ushort)
  if (wid == 0) {
    int carry = 0;
    for (int c8 = 0; c8 < NB / 64; c8++) {
      int v = cnt[c8 * 64 + lane];
      int x = v;
      for (int d = 1; d < 64; d <<= 1) {
        int y = __shfl_up(x, d, 64);
        if (lane >= d) x += y;
      }
      ofs[c8 * 64 + lane] = (unsigned short)(carry + x - v);
      carry += __shfl(x, 63, 64);
    }
    if (lane == 0) ntot_s = carry;
  }
  __syncthreads();
  for (int i = tid; i < NB; i += APPT) cnt[i] = ofs[i];
  __syncthreads();
  // pass B: scatter from registers (+ self)
#pragma unroll
  for (int k = 0; k < NE; k++) {
    unsigned v = tval[k];
    if (v != NOPE) {
      unsigned tr = v >> 16, tc = v & 0xFFFFu;
      int p1 = atomicAdd(&cnt[tr / RPB], 1);
      sorted[p1] = v;
      int p2 = atomicAdd(&cnt[tc / RPB], 1);
      sorted[p2] = (tc << 16) | tr;
      unsigned a = aval[k];
      if (a != NOPE) {
        int p3 = atomicAdd(&cnt[(a >> 16) / RPB], 1);
        sorted[p3] = a;
      }
    }
  }
  for (int i = i0 + tid; i < i1; i += APPT) {
    int p = atomicAdd(&cnt[i / RPB], 1);
    sorted[p] = ((unsigned)i << 16) | (unsigned)i;
  }
  __syncthreads();
  // reserve global space: one atomicAdd per bucket per block
  int ntot = ntot_s;
  for (int b = tid; b < NB; b += APPT) {
    int end = (b < NB - 1) ? (int)ofs[b + 1] : ntot;
    int len = end - (int)ofs[b];
    cnt[b] = len ? atomicAdd(&cursors[b * CURSTRIDE], len) : 0;
  }
  __syncthreads();
  // coalesced flush (store local row id in high 16)
  for (int j = tid; j < ntot; j += APPT) {
    unsigned item = sorted[j];
    unsigned r = item >> 16;
    unsigned b = r / RPB;
    unsigned lr = r - b * RPB;
    int idx = cnt[b] + (j - (int)ofs[b]);
    if (idx < CAP) bucketmem[b * CAP + idx] = (lr << 16) | (item & 0xFFFFu);
  }
}

// ---------------- dedup: 2 buckets per block, wave-per-row bitmaps ----------
__global__ __launch_bounds__(DT) void k_dedup(unsigned *bucketmem,
                                              const int *cursors, int *uniq_cnt) {
  __shared__ unsigned short arr[2][CAP];   // 32 KB
  __shared__ int cnt[2][RPB];
  __shared__ int rowend[2][RPB];
  __shared__ int curs[2][RPB];
  __shared__ int rowoff[2][RPB];
  __shared__ unsigned bm[8][WORDS];        // 40 KB wave-private bitmaps
  __shared__ unsigned sm[8][SWORDS];

  int tid = threadIdx.x, lane = tid & 63, wid = tid >> 6;
  int h = wid >> 2;          // half 0/1
  int hw = wid & 3;          // wave within half
  int t2 = tid & 255;        // thread within half
  int b = blockIdx.x * 2 + h;
  int rowbase = b * RPB;
  bool active = rowbase < NN;

  int n = 0;
  const unsigned *src = bucketmem + (size_t)b * CAP;
  if (active) { n = cursors[b * CURSTRIDE]; if (n > CAP) n = CAP; }

  for (int i = t2; i < RPB; i += 256) cnt[h][i] = 0;
  __syncthreads();
  if (active)
    for (int j = t2; j < n; j += 256) atomicAdd(&cnt[h][src[j] >> 16], 1);
  __syncthreads();
  // per-half wave0 parallel exclusive scan over RPB rows
  if (hw == 0 && active) {
    int v = (lane < RPB) ? cnt[h][lane] : 0;
    int x = v;
    for (int d = 1; d < 64; d <<= 1) {
      int y = __shfl_up(x, d, 64);
      if (lane >= d) x += y;
    }
    if (lane < RPB) { curs[h][lane] = x - v; rowend[h][lane] = x; }
  }
  __syncthreads();
  if (active)
    for (int j = t2; j < n; j += 256) {
      unsigned v = src[j];
      int p = atomicAdd(&curs[h][v >> 16], 1);
      arr[h][p] = (unsigned short)v;
    }
  for (int w = lane; w < WORDS; w += 64) bm[wid][w] = 0u;
  if (lane < SWORDS) sm[wid][lane] = 0u;
  __syncthreads();

  if (active)
    for (int r = hw; r < RPB; r += 4) {
      int s1 = rowend[h][r], s0 = s1 - cnt[h][r];
      for (int j = s0 + lane; j < s1; j += 64) {
        unsigned c = arr[h][j];
        atomicOr(&bm[wid][c >> 5], 1u << (c & 31));
        atomicOr(&sm[wid][c >> 10], 1u << ((c >> 5) & 31));
      }
      unsigned s = (lane < SWORDS) ? sm[wid][lane] : 0u;
      int m = 0;
      unsigned t = s;
      while (t) {
        int w = (lane << 5) + (__ffs(t) - 1);
        t &= t - 1;
        m += __popc(bm[wid][w]);
      }
      int x = m;
      for (int d = 1; d < 64; d <<= 1) {
        int y = __shfl_up(x, d, 64);
        if (lane >= d) x += y;
      }
      int u = __shfl(x, 63, 64);
      int pos = s0 + (x - m);
      t = s;
      while (t) {
        int w = (lane << 5) + (__ffs(t) - 1);
        t &= t - 1;
        unsigned mm = bm[wid][w];
        bm[wid][w] = 0u;
        while (mm) {
          int bit = __ffs(mm) - 1;
          mm &= mm - 1;
          arr[h][pos++] = (unsigned short)((w << 5) + bit);
        }
      }
      if (lane < SWORDS) sm[wid][lane] = 0u;
      if (lane == 0) cnt[h][r] = u;
    }
  __syncthreads();
  // per-half wave0 parallel exclusive scan of unique counts
  if (hw == 0 && active) {
    int v = (lane < RPB) ? cnt[h][lane] : 0;
    int x = v;
    for (int d = 1; d < 64; d <<= 1) {
      int y = __shfl_up(x, d, 64);
      if (lane >= d) x += y;
    }
    if (lane < RPB) rowoff[h][lane] = x - v;
    if (lane == RPB - 1) uniq_cnt[b] = x;
  }
  if (!active && t2 == 0) uniq_cnt[b] = 0;
  __syncthreads();
  // write uniques as packed (row<<16)|col — ascending == hash order
  if (active) {
    unsigned *dst = bucketmem + (size_t)b * CAP;
    for (int r = hw; r < RPB; r += 4) {
      int s0 = r ? rowend[h][r - 1] : 0;
      int u = cnt[h][r], o = rowoff[h][r];
      unsigned rowpack = (unsigned)(rowbase + r) << 16;
      for (int j = lane; j < u; j += 64)
        dst[o + j] = rowpack | (unsigned)arr[h][s0 + j];
    }
  }
}

// ---------------- emit (fused offset-reduction + diag) ----------------
__global__ __launch_bounds__(256) void k_emit(const unsigned *bucketmem,
                                              const int *uniq_cnt, float *out,
                                              int E, int U) {
  __shared__ int part[4];
  int b = blockIdx.x;
  int tid = threadIdx.x, lane = tid & 63, wid = tid >> 6;
  // ob = sum of uniq_cnt[0..b) via masked butterfly reduction
  int acc = 0;
  for (int i = tid; i < NB; i += 256)
    if (i < b) acc += uniq_cnt[i];
  for (int d = 1; d < 64; d <<= 1) acc += __shfl_xor(acc, d, 64);
  if (lane == 0) part[wid] = acc;
  __syncthreads();
  int ob = part[0] + part[1] + part[2] + part[3];
  int ub = uniq_cnt[b];
  const unsigned *src = bucketmem + (size_t)b * CAP;
  int base3 = 3 * E;
  for (int j = tid; j < ub; j += 256) {
    unsigned h = src[j];
    unsigned r = h >> 16;
    unsigned c = h & 0xFFFFu;
    int idx = ob + j;
    if (idx < U) {
      out[base3 + idx] = (float)r;
      out[base3 + U + idx] = (float)c;
      out[base3 + 2 * U + idx] = 1.0f;
    }
  }
  if (b == NB - 1 && tid == 0) {
    int C = ob + ub;
    if (C != U) {
      int d = C - U; if (d < 0) d = -d; if (d > 60000) d = 60000;
      out[base3] = (float)(300000 + d); // sentinel (should never fire)
    }
  }
}

// ---------------- launch ----------------
extern "C" void kernel_launch(void *const *d_in, const int *in_sizes, int n_in,
                              void *d_out, int out_size, void *d_ws,
                              size_t ws_size, hipStream_t stream) {
  const int *rows = (const int *)d_in[0];
  const int *cols = (const int *)d_in[1];
  const int *seeds = (const int *)d_in[3];
  const int E = in_sizes[0];
  const int ns = in_sizes[3];
  float *out = (float *)d_out;
  const int U = (out_size - 3 * E) / 3;

  // ---- workspace carve ----
  int *I = (int *)d_ws;
  int *deg = I;      I += NN;               // zeroed in k_level0
  int *cursors = I;  I += NB * CURSTRIDE;   // zeroed in k_level0 (64KB)
  int *uniq_cnt = I; I += NB;               // fully written by k_dedup
  unsigned char *cur = (unsigned char *)I;  // 3*NN bytes zeroed by k_zero16
  unsigned char *touched = cur + NN;
  unsigned char *mask_bfs = touched + NN;
  size_t zero_bytes = (size_t)(3 * NN);     // cur+touched+mask_bfs only
  int *J = (int *)(mask_bfs + NN);
  int *tem_num = J;  J += 1;
  J += 1; // pad to 8B
  int *mask_part = J; J += 40;              // popcount partials (fully written)
  unsigned short *mask_idx = (unsigned short *)J;
  J += NN / 2; // 40000 ushorts = 20000 ints
  unsigned *bucketmem = (unsigned *)J; J += (size_t)NB * CAP; // 32 MB
  unsigned char *alive = (unsigned char *)J; // E bytes (fully written)

  // ---- host key derivation (v0): key(1)=(0,1); split(3); randint split(2) ----
  unsigned F[3][2];
  tf2x32(0u, 1u, 0u, 0u, F[0][0], F[0][1]); // kS
  tf2x32(0u, 1u, 0u, 1u, F[1][0], F[1][1]); // kR
  tf2x32(0u, 1u, 0u, 2u, F[2][0], F[2][1]); // kC
  unsigned K[3][4];
  for (int s = 0; s < 3; s++) {
    tf2x32(F[s][0], F[s][1], 0u, 0u, K[s][0], K[s][1]); // k1 (higher bits)
    tf2x32(F[s][0], F[s][1], 0u, 1u, K[s][2], K[s][3]); // k2 (lower bits)
  }

  dim3 b(256);
  int gE = (E + 255) / 256;
  int gSS = (SAMPN + 255) / 256; // covers ns=2000 too
  int gT = (E + EPB - 1) / EPB;  // 455; also covers self nodes (455*88>=NN)
  int n16 = (int)(zero_bytes / 16);

  k_zero16<<<(n16 + 255) / 256, b, 0, stream>>>((uint4 *)cur, n16);
  k_seed_samp<<<gSS, b, 0, stream>>>(seeds, ns, cur, mask_bfs,
                                     K[0][0], K[0][1], K[0][2], K[0][3]);
  k_level0<<<gE, b, 0, stream>>>(rows, cols, E, cur, alive, touched, mask_bfs,
                                 deg, cursors);
  k_level1_deg<<<gE, b, 0, stream>>>(rows, cols, E, touched, alive, deg,
                                     (const unsigned *)mask_bfs, mask_part);
  k_mask_extract<<<40, b, 0, stream>>>((const unsigned *)mask_bfs, mask_part,
                                       mask_idx, tem_num);
  k_append<<<gT, dim3(APPT), 0, stream>>>(rows, cols, alive, deg, mask_idx,
                                          tem_num, cursors, bucketmem, out,
                                          K[1][0], K[1][1], K[1][2], K[1][3],
                                          K[2][0], K[2][1], K[2][2], K[2][3], E);
  k_dedup<<<NB / 2, dim3(DT), 0, stream>>>(bucketmem, cursors, uniq_cnt);
  k_emit<<<NB, b, 0, stream>>>(bucketmem, uniq_cnt, out, E, U);
}